// Round 12
// baseline (636.016 us; speedup 1.0000x reference)
//
#include <hip/hip_runtime.h>
#include <math.h>

// SimilarityModel: seg = sigmoid( softmax(QK^T/32) @ v + c + cb ), v = rf·u scalar per token.
// Round 12: R8 + Q-in-register with 2-step-deep parity prefetch (kidx unroll-2,
// even steps own afA / odd own afB, reload AFTER the MFMA cluster -> no copies,
// no same-step waits). B-only 3-ring LDS (48KB), counted vmcnt(8), no-max softmax.

#define DD 1024
#define NN 12544
#define NSPLIT 5
#define NPART  10   // NSPLIT * 2 column-half waves
#define NTILES 49   // NN / 256 (column tiles)

typedef __attribute__((ext_vector_type(8))) short short8;
typedef __attribute__((ext_vector_type(4))) float f32x4;
typedef __attribute__((ext_vector_type(4))) unsigned short ushort4_t;
typedef unsigned short ushort_t;
typedef unsigned int uint32;

__device__ __forceinline__ ushort_t f2bf(float f) {
    union { float f; uint32 u; } v; v.f = f;
    uint32 u = v.u + 0x7FFF + ((v.u >> 16) & 1);   // RNE
    return (ushort_t)(u >> 16);
}

__device__ __forceinline__ void gload_lds16(const void* g, void* l) {
    __builtin_amdgcn_global_load_lds((const __attribute__((address_space(1))) uint32*)g,
                                     (__attribute__((address_space(3))) uint32*)l, 16, 0, 0);
}

// ---------------------------------------------------------------------------
// u[k] += sum_{d in slice} Wv[d,k]*cw[d]; blocks (0,y) also reduce c = bv·cw.
__global__ void k_u(const float* __restrict__ Wv, const float* __restrict__ cw,
                    const float* __restrict__ bv, float* __restrict__ u,
                    float* __restrict__ cptr) {
    const int t = threadIdx.x;
    const int k = blockIdx.x * 256 + t;
    const int d0 = blockIdx.y * 64;
    float acc = 0.f;
#pragma unroll 16
    for (int i = 0; i < 64; ++i) acc += Wv[(size_t)(d0 + i) * DD + k] * cw[d0 + i];
    atomicAdd(&u[k], acc);
    if (blockIdx.x == 0 && t < 64) {
        float ca = bv[d0 + t] * cw[d0 + t];
        for (int off = 32; off > 0; off >>= 1) ca += __shfl_down(ca, off);
        if (t == 0) atomicAdd(cptr, ca);
    }
}

// ---------------------------------------------------------------------------
// One pass over rf: produce xo (N,D) bf16, xa = rf+pe[sig] (N,D) bf16,
// and vsc[n] = sum_d rf[d,n]*u[d]. 64 tokens per block.
__global__ __launch_bounds__(256)
void k_prep(const float* __restrict__ rf, const int* __restrict__ sig,
            const float* __restrict__ pe, const float* __restrict__ u,
            ushort_t* __restrict__ xo, ushort_t* __restrict__ xa,
            float* __restrict__ vsc) {
    __shared__ ushort_t so[64][136];
    __shared__ ushort_t sa[64][136];
    __shared__ float pel[5 * 128];
    __shared__ float ul[128];
    __shared__ int sigl[64];
    __shared__ f32x4 red[16][16];
    const int t = threadIdx.x;
    const int n0 = blockIdx.x * 64;
    if (t < 64) sigl[t] = sig[n0 + t];
    __syncthreads();
    const int dl = t >> 4, tg = t & 15;
    const int sg[4] = {sigl[tg * 4], sigl[tg * 4 + 1], sigl[tg * 4 + 2], sigl[tg * 4 + 3]};
    const int tok = t >> 2, part = t & 3;
    f32x4 vacc = (f32x4)(0.f);

    for (int c = 0; c < 8; ++c) {
        const int d0 = c * 128;
        for (int i = t; i < 640; i += 256) pel[i] = pe[(i >> 7) * DD + d0 + (i & 127)];
        if (t < 128) ul[t] = u[d0 + t];
        __syncthreads();
#pragma unroll
        for (int s = 0; s < 8; ++s) {
            const int dli = s * 16 + dl;
            const f32x4 x = *(const f32x4*)&rf[(size_t)(d0 + dli) * NN + n0 + tg * 4];
            vacc += x * ul[dli];
            ushort_t oo[4], aa[4];
#pragma unroll
            for (int j = 0; j < 4; ++j) {
                oo[j] = f2bf(x[j]);
                aa[j] = f2bf(x[j] + pel[sg[j] * 128 + dli]);
            }
#pragma unroll
            for (int j = 0; j < 4; ++j) {
                so[tg * 4 + j][dli] = oo[j];
                sa[tg * 4 + j][dli] = aa[j];
            }
        }
        __syncthreads();
#pragma unroll
        for (int i = 0; i < 4; ++i) {
            const int off = part * 32 + i * 8;
            *(short8*)&xo[(size_t)(n0 + tok) * DD + d0 + off] = *(const short8*)&so[tok][off];
            *(short8*)&xa[(size_t)(n0 + tok) * DD + d0 + off] = *(const short8*)&sa[tok][off];
        }
        __syncthreads();
    }
    red[dl][tg] = vacc;
    __syncthreads();
    if (t < 64) {
        float s = 0.f;
#pragma unroll
        for (int i = 0; i < 16; ++i) s += ((const float*)&red[i][t >> 2])[t & 3];
        vsc[n0 + t] = s;
    }
}

// ---------------------------------------------------------------------------
// Cast Wq / Wk to bf16.
__global__ void k_wcast(const float* __restrict__ Wq, const float* __restrict__ Wk,
                        ushort_t* __restrict__ wqb, ushort_t* __restrict__ wkb) {
    const int idx = (blockIdx.x * 256 + threadIdx.x) * 8;
    const float* src = blockIdx.y ? Wk : Wq;
    ushort_t* dst = blockIdx.y ? wkb : wqb;
    f32x4 a = *(const f32x4*)&src[idx];
    f32x4 b = *(const f32x4*)&src[idx + 4];
    short8 o;
#pragma unroll
    for (int j = 0; j < 4; ++j) { o[j] = (short)f2bf(a[j]); o[4 + j] = (short)f2bf(b[j]); }
    *(short8*)&dst[idx] = o;
}

// ---------------------------------------------------------------------------
// Projection GEMM: out[n, d'] = bf16( scale*( sum_d x[n,d]*W[d',d] + bias[d'] ) ).
__global__ __launch_bounds__(256, 2)
void k_pgemm(const ushort_t* __restrict__ xb, const ushort_t* __restrict__ wb,
             const float* __restrict__ bias, float scale, ushort_t* __restrict__ outb) {
    __shared__ ushort_t as_[128 * 64];
    __shared__ ushort_t bs_[128 * 64];
    const int t = threadIdx.x;
    const int wv = t >> 6, ln = t & 63;
    const int wr = wv >> 1, wc = wv & 1;
    const int l15 = ln & 15, lhi = ln >> 4;
    const int n0 = blockIdx.x * 128;   // tokens
    const int m0 = blockIdx.y * 128;   // d'
    const int srow = wv * 32;
    const int lr = ln >> 3, lc = ln & 7;
    const int swz = lc ^ lr;

    f32x4 acc[4][4];
#pragma unroll
    for (int a = 0; a < 4; ++a)
#pragma unroll
        for (int b = 0; b < 4; ++b) acc[a][b] = (f32x4)(0.f);

    for (int kk = 0; kk < DD; kk += 64) {
        __syncthreads();
#pragma unroll
        for (int i = 0; i < 4; ++i) {
            const int tok = srow + i * 8 + lr;
            gload_lds16(wb + (size_t)(m0 + tok) * DD + kk + (swz << 3), as_ + (srow + i * 8) * 64);
            gload_lds16(xb + (size_t)(n0 + tok) * DD + kk + (swz << 3), bs_ + (srow + i * 8) * 64);
        }
        __syncthreads();
#pragma unroll
        for (int kp = 0; kp < 2; ++kp) {
            short8 af[4], bf_[4];
#pragma unroll
            for (int mi = 0; mi < 4; ++mi) {
                int r = wr * 64 + mi * 16 + l15;
                int cch = (kp * 4 + lhi) ^ (r & 7);
                af[mi] = *(const short8*)(as_ + r * 64 + cch * 8);
            }
#pragma unroll
            for (int ni = 0; ni < 4; ++ni) {
                int r = wc * 64 + ni * 16 + l15;
                int cch = (kp * 4 + lhi) ^ (r & 7);
                bf_[ni] = *(const short8*)(bs_ + r * 64 + cch * 8);
            }
#pragma unroll
            for (int mi = 0; mi < 4; ++mi)
#pragma unroll
                for (int ni = 0; ni < 4; ++ni)
                    acc[mi][ni] = __builtin_amdgcn_mfma_f32_16x16x32_bf16(
                        af[mi], bf_[ni], acc[mi][ni], 0, 0, 0);
        }
    }
    float bb[4][4];
#pragma unroll
    for (int mi = 0; mi < 4; ++mi) {
        f32x4 b4 = *(const f32x4*)&bias[m0 + wr * 64 + mi * 16 + lhi * 4];
#pragma unroll
        for (int r = 0; r < 4; ++r) bb[mi][r] = b4[r];
    }
#pragma unroll
    for (int mi = 0; mi < 4; ++mi)
#pragma unroll
        for (int ni = 0; ni < 4; ++ni) {
            ushort4_t o;
#pragma unroll
            for (int r = 0; r < 4; ++r) o[r] = f2bf((acc[mi][ni][r] + bb[mi][r]) * scale);
            *(ushort4_t*)&outb[(size_t)(n0 + wc * 64 + ni * 16 + l15) * DD +
                               m0 + wr * 64 + mi * 16 + lhi * 4] = o;
        }
}

// ---------------------------------------------------------------------------
// Fused MFMA scores + softmax (no max subtraction) + scalar-V sum.
// 256 threads = 4 waves (2M x 2N), block tile 128x256, wave tile 64x128, BK=32.
// Q in registers, 2-step-deep parity prefetch: even steps use+reload afA, odd afB;
// reload happens AFTER the MFMA cluster (no copies, no same-step waits).
// K staged in B-only 3-ring LDS (48 KiB) -> 2 blocks/CU. Counted vmcnt(8).
__global__ __launch_bounds__(256, 2)
void k_attn(const ushort_t* __restrict__ qb, const ushort_t* __restrict__ kb,
            const float* __restrict__ vsc, float* __restrict__ pl,
            float* __restrict__ pa) {
    __shared__ ushort_t Bs[3][256 * 32];
    const int t = threadIdx.x;
    const int wv = t >> 6, ln = t & 63;
    const int wm = wv >> 1, wn = wv & 1;     // wave tile: rows wm*64, cols wn*128
    const int l15 = ln & 15, lhi = ln >> 4;

    // XCD-aware bijective swizzle: 490 blocks, q=61, r=2.
    const int g = blockIdx.x;
    const int xcd = g & 7, gq = g >> 3;
    const int L = (xcd < 2) ? xcd * 62 + gq : 124 + (xcd - 2) * 61 + gq;
    const int bx = L / NSPLIT, split = L % NSPLIT;
    const int m0 = bx * 128;

    // staging coords: 64B rows (BK=32); chunk = 16B; swizzle chunk ^= (row>>1)&3
    const int srr = ln >> 2;          // row within 16-row group
    const int slc = ln & 3;           // chunk within row

    // per-lane Q fragment base: row m0 + wm*64 + mi*16 + l15, k-chunk lhi
    const ushort_t* qbase = qb + (size_t)(m0 + wm * 64 + l15) * DD + lhi * 8;

    float rl[4][4], ra[4][4];
#pragma unroll
    for (int a = 0; a < 4; ++a)
#pragma unroll
        for (int b = 0; b < 4; ++b) { rl[a][b] = 0.f; ra[a][b] = 0.f; }

    f32x4 acc[4][8];
#pragma unroll
    for (int a = 0; a < 4; ++a)
#pragma unroll
        for (int b = 0; b < 8; ++b) acc[a][b] = (f32x4)(0.f);

// stage one K-step's B tile (4 gloads/lane) into ring buffer BUF
#define STAGE(BUF, SNT, KKO)                                                      \
    {                                                                             \
        const int nn0_ = (SNT) * 256;                                            \
        ushort_t* Bd = &Bs[BUF][0];                                              \
        _Pragma("unroll")                                                        \
        for (int i = 0; i < 4; ++i) {                                            \
            const int row = wv * 64 + i * 16 + srr;                              \
            const int sc = slc ^ ((row >> 1) & 3);                               \
            gload_lds16(kb + (size_t)(nn0_ + row) * DD + (KKO) + sc * 8,         \
                        Bd + (wv * 64 + i * 16) * 32);                           \
        }                                                                        \
    }

// load Q fragment set for k-element-offset KQ into register array AF
#define QLOAD(AF, KQ)                                                             \
    {                                                                             \
        const size_t kq_ = (size_t)(KQ);                                         \
        _Pragma("unroll")                                                        \
        for (int mi = 0; mi < 4; ++mi)                                           \
            AF[mi] = *(const short8*)(qbase + (size_t)(mi * 16) * DD + kq_);     \
    }

// one K-step: vv prefetch (step 31), stage B(s+2), read B frags, MFMA with AF,
// reload AF with Q(s+2) (same parity), epilogue (step 31), counted wait, barrier.
#define STEP(AF, KIDX)                                                            \
    {                                                                             \
        const int kidx_ = (KIDX);                                                \
        float vv[8];                                                             \
        if (kidx_ == 31) {                                                       \
            _Pragma("unroll")                                                    \
            for (int ni = 0; ni < 8; ++ni)                                       \
                vv[ni] = vsc[n0 + wn * 128 + ni * 16 + l15];                     \
        }                                                                        \
        int nk2 = kidx_ + 2, nnt2 = nt;                                          \
        if (nk2 >= 32) { nk2 -= 32; nnt2 += NSPLIT; }                            \
        const bool st = (nnt2 < NTILES);                                         \
        if (st) {                                                                \
            int b2 = cur + 2; if (b2 >= 3) b2 -= 3;                              \
            STAGE(b2, nnt2, nk2 * 32);                                           \
        }                                                                        \
        const ushort_t* Bb = &Bs[cur][0];                                        \
        short8 bfr[8];                                                           \
        _Pragma("unroll")                                                        \
        for (int ni = 0; ni < 8; ++ni) {                                         \
            const int r = wn * 128 + ni * 16 + l15;                              \
            const int c = lhi ^ ((r >> 1) & 3);                                  \
            bfr[ni] = *(const short8*)(Bb + r * 32 + c * 8);                     \
        }                                                                        \
        __builtin_amdgcn_s_setprio(1);                                           \
        _Pragma("unroll")                                                        \
        for (int ni = 0; ni < 8; ++ni)                                           \
            _Pragma("unroll")                                                    \
            for (int mi = 0; mi < 4; ++mi)                                       \
                acc[mi][ni] = __builtin_amdgcn_mfma_f32_16x16x32_bf16(           \
                    AF[mi], bfr[ni], acc[mi][ni], 0, 0, 0);                      \
        __builtin_amdgcn_s_setprio(0);                                           \
        QLOAD(AF, ((kidx_ + 2) & 31) * 32);                                      \
        if (kidx_ == 31) {                                                       \
            _Pragma("unroll")                                                    \
            for (int mi = 0; mi < 4; ++mi) {                                     \
                _Pragma("unroll")                                                \
                for (int r = 0; r < 4; ++r) {                                    \
                    float sp = 0.f, sv = 0.f;                                    \
                    _Pragma("unroll")                                            \
                    for (int ni = 0; ni < 8; ++ni) {                             \
                        float p = __expf(acc[mi][ni][r]);                        \
                        sp += p; sv += p * vv[ni];                               \
                    }                                                            \
                    sp += __shfl_xor(sp, 1); sv += __shfl_xor(sv, 1);            \
                    sp += __shfl_xor(sp, 2); sv += __shfl_xor(sv, 2);            \
                    sp += __shfl_xor(sp, 4); sv += __shfl_xor(sv, 4);            \
                    sp += __shfl_xor(sp, 8); sv += __shfl_xor(sv, 8);            \
                    rl[mi][r] += sp;                                             \
                    ra[mi][r] += sv;                                             \
                }                                                                \
            }                                                                    \
            _Pragma("unroll")                                                    \
            for (int a = 0; a < 4; ++a)                                          \
                _Pragma("unroll")                                                \
                for (int b = 0; b < 8; ++b) acc[a][b] = (f32x4)(0.f);            \
        }                                                                        \
        if (st) asm volatile("s_waitcnt vmcnt(8)" ::: "memory");                 \
        else    asm volatile("s_waitcnt vmcnt(4)" ::: "memory");                 \
        __builtin_amdgcn_s_barrier();                                            \
        cur = (cur + 1 == 3) ? 0 : cur + 1;                                      \
    }

    // prologue: B(0), Q(0)->afA, B(1), Q(1)->afB; drain exactly {B0, Q0}
    short8 afA[4], afB[4];
    STAGE(0, split, 0);
    QLOAD(afA, 0);
    STAGE(1, split, 32);
    QLOAD(afB, 32);
    asm volatile("s_waitcnt vmcnt(8)" ::: "memory");
    __builtin_amdgcn_s_barrier();

    int cur = 0;
    for (int nt = split; nt < NTILES; nt += NSPLIT) {
        const int n0 = nt * 256;
        for (int kh = 0; kh < 16; ++kh) {
            STEP(afA, 2 * kh);
            STEP(afB, 2 * kh + 1);
        }
    }
#undef STEP
#undef QLOAD
#undef STAGE
    asm volatile("s_waitcnt vmcnt(0)" ::: "memory");
    // write partials: slab = split*2 + wn
    if (l15 == 0) {
        const size_t slab = (size_t)(split * 2 + wn) * NN;
#pragma unroll
        for (int mi = 0; mi < 4; ++mi)
#pragma unroll
            for (int r = 0; r < 4; ++r) {
                int row = m0 + wm * 64 + mi * 16 + lhi * 4 + r;
                pl[slab + row] = rl[mi][r];
                pa[slab + row] = ra[mi][r];
            }
    }
}

// ---------------------------------------------------------------------------
// Merge partials; add conv-head constants (c = bv·cw folded here) + sigmoid.
__global__ void k_comb(const float* __restrict__ pl, const float* __restrict__ pa,
                       const float* __restrict__ cptr, const float* __restrict__ cb,
                       float* __restrict__ out) {
    int n = blockIdx.x * 256 + threadIdx.x;
    float l = 0.f, a = 0.f;
#pragma unroll
    for (int s = 0; s < NPART; ++s) {
        l += pl[(size_t)s * NN + n];
        a += pa[(size_t)s * NN + n];
    }
    float x = a / l + cptr[0] + cb[0];
    out[n] = 1.f / (1.f + __expf(-x));
}

// ---------------------------------------------------------------------------
extern "C" void kernel_launch(void* const* d_in, const int* in_sizes, int n_in,
                              void* d_out, int out_size, void* d_ws, size_t ws_size,
                              hipStream_t stream) {
    const int* sig = (const int*)d_in[0];
    const float* rf = (const float*)d_in[1];
    const float* pe = (const float*)d_in[3];
    const float* Wq = (const float*)d_in[4];
    const float* bq = (const float*)d_in[5];
    const float* Wk = (const float*)d_in[6];
    const float* bk = (const float*)d_in[7];
    const float* Wv = (const float*)d_in[8];
    const float* bv = (const float*)d_in[9];
    const float* cw = (const float*)d_in[10];
    const float* cb = (const float*)d_in[11];
    float* out = (float*)d_out;

    ushort_t* buf0 = (ushort_t*)d_ws;             // xo, later qb
    ushort_t* buf1 = buf0 + (size_t)NN * DD;      // xa
    ushort_t* buf2 = buf1 + (size_t)NN * DD;      // kb
    ushort_t* wqb = buf2 + (size_t)NN * DD;
    ushort_t* wkb = wqb + (size_t)DD * DD;
    float* u = (float*)(wkb + (size_t)DD * DD);   // 1024
    float* cptr = u + 1024;                       // 16 reserved
    float* vsc = u + 1024 + 16;                   // NN
    float* pl = vsc + NN;                         // NPART*NN
    float* pa = pl + (size_t)NPART * NN;

    hipMemsetAsync(u, 0, (1024 + 16) * sizeof(float), stream);
    k_u<<<dim3(4, 16), 256, 0, stream>>>(Wv, cw, bv, u, cptr);
    k_prep<<<196, 256, 0, stream>>>(rf, sig, pe, u, buf0, buf1, vsc);
    k_wcast<<<dim3(512, 2), 256, 0, stream>>>(Wq, Wk, wqb, wkb);
    k_pgemm<<<dim3(98, 8), 256, 0, stream>>>(buf0, wkb, bk, 1.0f, buf2);      // K
    k_pgemm<<<dim3(98, 8), 256, 0, stream>>>(buf1, wqb, bq, 0.03125f, buf0);  // Q
    k_attn<<<490, 256, 0, stream>>>(buf0, buf2, vsc, pl, pa);
    k_comb<<<NN / 256, 256, 0, stream>>>(pl, pa, cptr, cb, out);
}

// Round 13
// 514.694 us; speedup vs baseline: 1.2357x; 1.2357x over previous
//
#include <hip/hip_runtime.h>
#include <math.h>

// SimilarityModel: seg = sigmoid( softmax(QK^T/32) @ v + c + cb ), v = rf·u scalar per token.
// Round 13: consolidation. k_attn = R8 verbatim (proven 394us: 128x256 tile, BK=32,
// 3-ring LDS, counted vmcnt(6), no-max softmax). k_pgemm ported to the same
// ring-3/counted-vmcnt structure (was 2-barrier drain-0).

#define DD 1024
#define NN 12544
#define NSPLIT 5
#define NPART  10   // NSPLIT * 2 column-half waves
#define NTILES 49   // NN / 256 (column tiles)

typedef __attribute__((ext_vector_type(8))) short short8;
typedef __attribute__((ext_vector_type(4))) float f32x4;
typedef __attribute__((ext_vector_type(4))) unsigned short ushort4_t;
typedef unsigned short ushort_t;
typedef unsigned int uint32;

__device__ __forceinline__ ushort_t f2bf(float f) {
    union { float f; uint32 u; } v; v.f = f;
    uint32 u = v.u + 0x7FFF + ((v.u >> 16) & 1);   // RNE
    return (ushort_t)(u >> 16);
}

__device__ __forceinline__ void gload_lds16(const void* g, void* l) {
    __builtin_amdgcn_global_load_lds((const __attribute__((address_space(1))) uint32*)g,
                                     (__attribute__((address_space(3))) uint32*)l, 16, 0, 0);
}

// ---------------------------------------------------------------------------
// u[k] += sum_{d in slice} Wv[d,k]*cw[d]; blocks (0,y) also reduce c = bv·cw.
__global__ void k_u(const float* __restrict__ Wv, const float* __restrict__ cw,
                    const float* __restrict__ bv, float* __restrict__ u,
                    float* __restrict__ cptr) {
    const int t = threadIdx.x;
    const int k = blockIdx.x * 256 + t;
    const int d0 = blockIdx.y * 64;
    float acc = 0.f;
#pragma unroll 16
    for (int i = 0; i < 64; ++i) acc += Wv[(size_t)(d0 + i) * DD + k] * cw[d0 + i];
    atomicAdd(&u[k], acc);
    if (blockIdx.x == 0 && t < 64) {
        float ca = bv[d0 + t] * cw[d0 + t];
        for (int off = 32; off > 0; off >>= 1) ca += __shfl_down(ca, off);
        if (t == 0) atomicAdd(cptr, ca);
    }
}

// ---------------------------------------------------------------------------
// One pass over rf: produce xo (N,D) bf16, xa = rf+pe[sig] (N,D) bf16,
// and vsc[n] = sum_d rf[d,n]*u[d]. 64 tokens per block.
__global__ __launch_bounds__(256)
void k_prep(const float* __restrict__ rf, const int* __restrict__ sig,
            const float* __restrict__ pe, const float* __restrict__ u,
            ushort_t* __restrict__ xo, ushort_t* __restrict__ xa,
            float* __restrict__ vsc) {
    __shared__ ushort_t so[64][136];
    __shared__ ushort_t sa[64][136];
    __shared__ float pel[5 * 128];
    __shared__ float ul[128];
    __shared__ int sigl[64];
    __shared__ f32x4 red[16][16];
    const int t = threadIdx.x;
    const int n0 = blockIdx.x * 64;
    if (t < 64) sigl[t] = sig[n0 + t];
    __syncthreads();
    const int dl = t >> 4, tg = t & 15;
    const int sg[4] = {sigl[tg * 4], sigl[tg * 4 + 1], sigl[tg * 4 + 2], sigl[tg * 4 + 3]};
    const int tok = t >> 2, part = t & 3;
    f32x4 vacc = (f32x4)(0.f);

    for (int c = 0; c < 8; ++c) {
        const int d0 = c * 128;
        for (int i = t; i < 640; i += 256) pel[i] = pe[(i >> 7) * DD + d0 + (i & 127)];
        if (t < 128) ul[t] = u[d0 + t];
        __syncthreads();
#pragma unroll
        for (int s = 0; s < 8; ++s) {
            const int dli = s * 16 + dl;
            const f32x4 x = *(const f32x4*)&rf[(size_t)(d0 + dli) * NN + n0 + tg * 4];
            vacc += x * ul[dli];
            ushort_t oo[4], aa[4];
#pragma unroll
            for (int j = 0; j < 4; ++j) {
                oo[j] = f2bf(x[j]);
                aa[j] = f2bf(x[j] + pel[sg[j] * 128 + dli]);
            }
#pragma unroll
            for (int j = 0; j < 4; ++j) {
                so[tg * 4 + j][dli] = oo[j];
                sa[tg * 4 + j][dli] = aa[j];
            }
        }
        __syncthreads();
#pragma unroll
        for (int i = 0; i < 4; ++i) {
            const int off = part * 32 + i * 8;
            *(short8*)&xo[(size_t)(n0 + tok) * DD + d0 + off] = *(const short8*)&so[tok][off];
            *(short8*)&xa[(size_t)(n0 + tok) * DD + d0 + off] = *(const short8*)&sa[tok][off];
        }
        __syncthreads();
    }
    red[dl][tg] = vacc;
    __syncthreads();
    if (t < 64) {
        float s = 0.f;
#pragma unroll
        for (int i = 0; i < 16; ++i) s += ((const float*)&red[i][t >> 2])[t & 3];
        vsc[n0 + t] = s;
    }
}

// ---------------------------------------------------------------------------
// Cast Wq / Wk to bf16.
__global__ void k_wcast(const float* __restrict__ Wq, const float* __restrict__ Wk,
                        ushort_t* __restrict__ wqb, ushort_t* __restrict__ wkb) {
    const int idx = (blockIdx.x * 256 + threadIdx.x) * 8;
    const float* src = blockIdx.y ? Wk : Wq;
    ushort_t* dst = blockIdx.y ? wkb : wqb;
    f32x4 a = *(const f32x4*)&src[idx];
    f32x4 b = *(const f32x4*)&src[idx + 4];
    short8 o;
#pragma unroll
    for (int j = 0; j < 4; ++j) { o[j] = (short)f2bf(a[j]); o[4 + j] = (short)f2bf(b[j]); }
    *(short8*)&dst[idx] = o;
}

// ---------------------------------------------------------------------------
// Projection GEMM: out[n, d'] = bf16( scale*( sum_d x[n,d]*W[d',d] + bias[d'] ) ).
// Round 13: ring-3 LDS (2 x 8KB per buf = 48KB), counted vmcnt(4) per step,
// 4 waves 2x2, wave tile 64x64, BK=32 — same pipeline skeleton as k_attn.
__global__ __launch_bounds__(256, 2)
void k_pgemm(const ushort_t* __restrict__ xb, const ushort_t* __restrict__ wb,
             const float* __restrict__ bias, float scale, ushort_t* __restrict__ outb) {
    __shared__ ushort_t Ws_[3][128 * 32];   // W rows (d')
    __shared__ ushort_t Xs_[3][128 * 32];   // x rows (tokens)
    const int t = threadIdx.x;
    const int wv = t >> 6, ln = t & 63;
    const int wr = wv >> 1, wc = wv & 1;
    const int l15 = ln & 15, lhi = ln >> 4;
    const int n0 = blockIdx.x * 128;   // tokens
    const int m0 = blockIdx.y * 128;   // d'
    const int srr = ln >> 2;           // row within 16-row group
    const int slc = ln & 3;            // chunk within row

    f32x4 acc[4][4];
#pragma unroll
    for (int a = 0; a < 4; ++a)
#pragma unroll
        for (int b = 0; b < 4; ++b) acc[a][b] = (f32x4)(0.f);

#define PSTAGE(BUF, KKO)                                                          \
    {                                                                             \
        ushort_t* Wd = &Ws_[BUF][0];                                              \
        ushort_t* Xd = &Xs_[BUF][0];                                              \
        _Pragma("unroll")                                                         \
        for (int i = 0; i < 2; ++i) {                                             \
            const int row = wv * 32 + i * 16 + srr;                               \
            const int sc = slc ^ ((row >> 1) & 3);                                \
            gload_lds16(wb + (size_t)(m0 + row) * DD + (KKO) + sc * 8,            \
                        Wd + (wv * 32 + i * 16) * 32);                            \
            gload_lds16(xb + (size_t)(n0 + row) * DD + (KKO) + sc * 8,            \
                        Xd + (wv * 32 + i * 16) * 32);                            \
        }                                                                         \
    }

    PSTAGE(0, 0);
    PSTAGE(1, 32);
    asm volatile("s_waitcnt vmcnt(4)" ::: "memory");
    __builtin_amdgcn_s_barrier();

    int cur = 0;
    for (int kidx = 0; kidx < 32; ++kidx) {
        const bool st = (kidx + 2 < 32);
        if (st) {
            int b2 = cur + 2; if (b2 >= 3) b2 -= 3;
            PSTAGE(b2, (kidx + 2) * 32);
        }
        const ushort_t* Wb = &Ws_[cur][0];
        const ushort_t* Xb = &Xs_[cur][0];
        short8 af[4], bf_[4];
#pragma unroll
        for (int mi = 0; mi < 4; ++mi) {
            const int r = wr * 64 + mi * 16 + l15;
            const int c = lhi ^ ((r >> 1) & 3);
            af[mi] = *(const short8*)(Wb + r * 32 + c * 8);
        }
#pragma unroll
        for (int ni = 0; ni < 4; ++ni) {
            const int r = wc * 64 + ni * 16 + l15;
            const int c = lhi ^ ((r >> 1) & 3);
            bf_[ni] = *(const short8*)(Xb + r * 32 + c * 8);
        }
        __builtin_amdgcn_s_setprio(1);
#pragma unroll
        for (int mi = 0; mi < 4; ++mi)
#pragma unroll
            for (int ni = 0; ni < 4; ++ni)
                acc[mi][ni] = __builtin_amdgcn_mfma_f32_16x16x32_bf16(
                    af[mi], bf_[ni], acc[mi][ni], 0, 0, 0);
        __builtin_amdgcn_s_setprio(0);
        if (st) asm volatile("s_waitcnt vmcnt(4)" ::: "memory");
        else    asm volatile("s_waitcnt vmcnt(0)" ::: "memory");
        __builtin_amdgcn_s_barrier();
        cur = (cur + 1 == 3) ? 0 : cur + 1;
    }
#undef PSTAGE

    float bb[4][4];
#pragma unroll
    for (int mi = 0; mi < 4; ++mi) {
        f32x4 b4 = *(const f32x4*)&bias[m0 + wr * 64 + mi * 16 + lhi * 4];
#pragma unroll
        for (int r = 0; r < 4; ++r) bb[mi][r] = b4[r];
    }
#pragma unroll
    for (int mi = 0; mi < 4; ++mi)
#pragma unroll
        for (int ni = 0; ni < 4; ++ni) {
            ushort4_t o;
#pragma unroll
            for (int r = 0; r < 4; ++r) o[r] = f2bf((acc[mi][ni][r] + bb[mi][r]) * scale);
            *(ushort4_t*)&outb[(size_t)(n0 + wc * 64 + ni * 16 + l15) * DD +
                               m0 + wr * 64 + mi * 16 + lhi * 4] = o;
        }
}

// ---------------------------------------------------------------------------
// Fused MFMA scores + softmax (no max subtraction; scores bounded) + scalar-V sum.
// R8 verbatim: 256 threads = 4 waves (2M x 2N), block tile 128x256, wave 64x128,
// BK=32, 3-ring LDS (72 KiB) -> 2 blocks/CU, stage 2 ahead, counted vmcnt(6).
__global__ __launch_bounds__(256, 2)
void k_attn(const ushort_t* __restrict__ qb, const ushort_t* __restrict__ kb,
            const float* __restrict__ vsc, float* __restrict__ pl,
            float* __restrict__ pa) {
    __shared__ ushort_t As[3][128 * 32];
    __shared__ ushort_t Bs[3][256 * 32];
    const int t = threadIdx.x;
    const int wv = t >> 6, ln = t & 63;
    const int wm = wv >> 1, wn = wv & 1;     // wave tile: rows wm*64, cols wn*128
    const int l15 = ln & 15, lhi = ln >> 4;

    // XCD-aware bijective swizzle: 490 blocks, q=61, r=2.
    const int g = blockIdx.x;
    const int xcd = g & 7, gq = g >> 3;
    const int L = (xcd < 2) ? xcd * 62 + gq : 124 + (xcd - 2) * 61 + gq;
    const int bx = L / NSPLIT, split = L % NSPLIT;
    const int m0 = bx * 128;

    // staging coords: 64B rows (BK=32); chunk = 16B; swizzle chunk ^= (row>>1)&3
    const int srr = ln >> 2;          // row within 16-row group
    const int slc = ln & 3;           // chunk within row

    float rl[4][4], ra[4][4];
#pragma unroll
    for (int a = 0; a < 4; ++a)
#pragma unroll
        for (int b = 0; b < 4; ++b) { rl[a][b] = 0.f; ra[a][b] = 0.f; }

    f32x4 acc[4][8];
#pragma unroll
    for (int a = 0; a < 4; ++a)
#pragma unroll
        for (int b = 0; b < 8; ++b) acc[a][b] = (f32x4)(0.f);

// stage one K-step's A+B tiles (6 gloads/lane) into ring buffer BUF
#define STAGE(BUF, SNT, KKO)                                                      \
    {                                                                             \
        const int nn0_ = (SNT) * 256;                                             \
        ushort_t* Ad = &As[BUF][0];                                               \
        ushort_t* Bd = &Bs[BUF][0];                                               \
        _Pragma("unroll")                                                         \
        for (int i = 0; i < 2; ++i) {                                             \
            const int row = wv * 32 + i * 16 + srr;                               \
            const int sc = slc ^ ((row >> 1) & 3);                                \
            gload_lds16(qb + (size_t)(m0 + row) * DD + (KKO) + sc * 8,            \
                        Ad + (wv * 32 + i * 16) * 32);                            \
        }                                                                         \
        _Pragma("unroll")                                                         \
        for (int i = 0; i < 4; ++i) {                                             \
            const int row = wv * 64 + i * 16 + srr;                               \
            const int sc = slc ^ ((row >> 1) & 3);                                \
            gload_lds16(kb + (size_t)(nn0_ + row) * DD + (KKO) + sc * 8,          \
                        Bd + (wv * 64 + i * 16) * 32);                            \
        }                                                                         \
    }

    // prologue: stage steps 0 and 1; wait for step 0 only (6 newest may remain)
    STAGE(0, split, 0);
    STAGE(1, split, 32);
    asm volatile("s_waitcnt vmcnt(6)" ::: "memory");
    __builtin_amdgcn_s_barrier();

    int cur = 0;
    for (int nt = split; nt < NTILES; nt += NSPLIT) {
        const int n0 = nt * 256;
        for (int kidx = 0; kidx < 32; ++kidx) {
            // epilogue vv prefetch FIRST so its wait is counted, not a drain
            float vv[8];
            if (kidx == 31) {
#pragma unroll
                for (int ni = 0; ni < 8; ++ni) vv[ni] = vsc[n0 + wn * 128 + ni * 16 + l15];
            }
            // stage step s+2 into ring buffer (s+2)%3
            int nk2 = kidx + 2, nnt2 = nt;
            if (nk2 >= 32) { nk2 -= 32; nnt2 += NSPLIT; }
            const bool st = (nnt2 < NTILES);
            if (st) {
                int b2 = cur + 2; if (b2 >= 3) b2 -= 3;
                STAGE(b2, nnt2, nk2 * 32);
            }
            // fragment reads from current buffer (2-way bank aliasing max = free)
            const ushort_t* Ab = &As[cur][0];
            const ushort_t* Bb = &Bs[cur][0];
            short8 af[4], bfr[8];
#pragma unroll
            for (int mi = 0; mi < 4; ++mi) {
                const int r = wm * 64 + mi * 16 + l15;
                const int c = lhi ^ ((r >> 1) & 3);
                af[mi] = *(const short8*)(Ab + r * 32 + c * 8);
            }
#pragma unroll
            for (int ni = 0; ni < 8; ++ni) {
                const int r = wn * 128 + ni * 16 + l15;
                const int c = lhi ^ ((r >> 1) & 3);
                bfr[ni] = *(const short8*)(Bb + r * 32 + c * 8);
            }
            __builtin_amdgcn_s_setprio(1);
#pragma unroll
            for (int ni = 0; ni < 8; ++ni)
#pragma unroll
                for (int mi = 0; mi < 4; ++mi)
                    acc[mi][ni] = __builtin_amdgcn_mfma_f32_16x16x32_bf16(
                        af[mi], bfr[ni], acc[mi][ni], 0, 0, 0);
            __builtin_amdgcn_s_setprio(0);

            if (kidx == 31) {
                // ---- softmax epilogue, no max subtraction (shift-invariant) ----
#pragma unroll
                for (int mi = 0; mi < 4; ++mi) {
#pragma unroll
                    for (int r = 0; r < 4; ++r) {
                        float sp = 0.f, sv = 0.f;
#pragma unroll
                        for (int ni = 0; ni < 8; ++ni) {
                            float p = __expf(acc[mi][ni][r]);
                            sp += p; sv += p * vv[ni];
                        }
                        sp += __shfl_xor(sp, 1); sv += __shfl_xor(sv, 1);
                        sp += __shfl_xor(sp, 2); sv += __shfl_xor(sv, 2);
                        sp += __shfl_xor(sp, 4); sv += __shfl_xor(sv, 4);
                        sp += __shfl_xor(sp, 8); sv += __shfl_xor(sv, 8);
                        rl[mi][r] += sp;
                        ra[mi][r] += sv;
                    }
                }
#pragma unroll
                for (int a = 0; a < 4; ++a)
#pragma unroll
                    for (int b = 0; b < 8; ++b) acc[a][b] = (f32x4)(0.f);
            }
            // T4: wait only for the PREVIOUS step's loads (6 newest outstanding ok)
            if (st) asm volatile("s_waitcnt vmcnt(6)" ::: "memory");
            else    asm volatile("s_waitcnt vmcnt(0)" ::: "memory");
            __builtin_amdgcn_s_barrier();
            cur = (cur + 1 == 3) ? 0 : cur + 1;
        }
    }
#undef STAGE
    // write partials: slab = split*2 + wn
    if (l15 == 0) {
        const size_t slab = (size_t)(split * 2 + wn) * NN;
#pragma unroll
        for (int mi = 0; mi < 4; ++mi)
#pragma unroll
            for (int r = 0; r < 4; ++r) {
                int row = m0 + wm * 64 + mi * 16 + lhi * 4 + r;
                pl[slab + row] = rl[mi][r];
                pa[slab + row] = ra[mi][r];
            }
    }
}

// ---------------------------------------------------------------------------
// Merge partials; add conv-head constants (c = bv·cw folded here) + sigmoid.
__global__ void k_comb(const float* __restrict__ pl, const float* __restrict__ pa,
                       const float* __restrict__ cptr, const float* __restrict__ cb,
                       float* __restrict__ out) {
    int n = blockIdx.x * 256 + threadIdx.x;
    float l = 0.f, a = 0.f;
#pragma unroll
    for (int s = 0; s < NPART; ++s) {
        l += pl[(size_t)s * NN + n];
        a += pa[(size_t)s * NN + n];
    }
    float x = a / l + cptr[0] + cb[0];
    out[n] = 1.f / (1.f + __expf(-x));
}

// ---------------------------------------------------------------------------
extern "C" void kernel_launch(void* const* d_in, const int* in_sizes, int n_in,
                              void* d_out, int out_size, void* d_ws, size_t ws_size,
                              hipStream_t stream) {
    const int* sig = (const int*)d_in[0];
    const float* rf = (const float*)d_in[1];
    const float* pe = (const float*)d_in[3];
    const float* Wq = (const float*)d_in[4];
    const float* bq = (const float*)d_in[5];
    const float* Wk = (const float*)d_in[6];
    const float* bk = (const float*)d_in[7];
    const float* Wv = (const float*)d_in[8];
    const float* bv = (const float*)d_in[9];
    const float* cw = (const float*)d_in[10];
    const float* cb = (const float*)d_in[11];
    float* out = (float*)d_out;

    ushort_t* buf0 = (ushort_t*)d_ws;             // xo, later qb
    ushort_t* buf1 = buf0 + (size_t)NN * DD;      // xa
    ushort_t* buf2 = buf1 + (size_t)NN * DD;      // kb
    ushort_t* wqb = buf2 + (size_t)NN * DD;
    ushort_t* wkb = wqb + (size_t)DD * DD;
    float* u = (float*)(wkb + (size_t)DD * DD);   // 1024
    float* cptr = u + 1024;                       // 16 reserved
    float* vsc = u + 1024 + 16;                   // NN
    float* pl = vsc + NN;                         // NPART*NN
    float* pa = pl + (size_t)NPART * NN;

    hipMemsetAsync(u, 0, (1024 + 16) * sizeof(float), stream);
    k_u<<<dim3(4, 16), 256, 0, stream>>>(Wv, cw, bv, u, cptr);
    k_prep<<<196, 256, 0, stream>>>(rf, sig, pe, u, buf0, buf1, vsc);
    k_wcast<<<dim3(512, 2), 256, 0, stream>>>(Wq, Wk, wqb, wkb);
    k_pgemm<<<dim3(98, 8), 256, 0, stream>>>(buf0, wkb, bk, 1.0f, buf2);      // K
    k_pgemm<<<dim3(98, 8), 256, 0, stream>>>(buf1, wqb, bq, 0.03125f, buf0);  // Q
    k_attn<<<490, 256, 0, stream>>>(buf0, buf2, vsc, pl, pa);
    k_comb<<<NN / 256, 256, 0, stream>>>(pl, pa, cptr, cb, out);
}

// Round 14
// 482.175 us; speedup vs baseline: 1.3191x; 1.0674x over previous
//
#include <hip/hip_runtime.h>
#include <math.h>

// SimilarityModel: seg = sigmoid( softmax(QK^T/32) @ v + c + cb ), v = rf·u scalar per token.
// Round 14: consolidation. k_attn = R8 structure (proven ~395us). k_pgemm reverted to
// the R3/R8-proven BK=64 2-barrier version (R13's ring-3 port regressed it).

#define DD 1024
#define NN 12544
#define NSPLIT 5
#define NPART  10   // NSPLIT * 2 column-half waves
#define NTILES 49   // NN / 256 (column tiles)

typedef __attribute__((ext_vector_type(8))) short short8;
typedef __attribute__((ext_vector_type(4))) float f32x4;
typedef __attribute__((ext_vector_type(4))) unsigned short ushort4_t;
typedef unsigned short ushort_t;
typedef unsigned int uint32;

__device__ __forceinline__ ushort_t f2bf(float f) {
    union { float f; uint32 u; } v; v.f = f;
    uint32 u = v.u + 0x7FFF + ((v.u >> 16) & 1);   // RNE
    return (ushort_t)(u >> 16);
}

__device__ __forceinline__ void gload_lds16(const void* g, void* l) {
    __builtin_amdgcn_global_load_lds((const __attribute__((address_space(1))) uint32*)g,
                                     (__attribute__((address_space(3))) uint32*)l, 16, 0, 0);
}

// ---------------------------------------------------------------------------
// u[k] += sum_{d in slice} Wv[d,k]*cw[d]; blocks (0,y) also reduce c = bv·cw.
__global__ void k_u(const float* __restrict__ Wv, const float* __restrict__ cw,
                    const float* __restrict__ bv, float* __restrict__ u,
                    float* __restrict__ cptr) {
    const int t = threadIdx.x;
    const int k = blockIdx.x * 256 + t;
    const int d0 = blockIdx.y * 64;
    float acc = 0.f;
#pragma unroll 16
    for (int i = 0; i < 64; ++i) acc += Wv[(size_t)(d0 + i) * DD + k] * cw[d0 + i];
    atomicAdd(&u[k], acc);
    if (blockIdx.x == 0 && t < 64) {
        float ca = bv[d0 + t] * cw[d0 + t];
        for (int off = 32; off > 0; off >>= 1) ca += __shfl_down(ca, off);
        if (t == 0) atomicAdd(cptr, ca);
    }
}

// ---------------------------------------------------------------------------
// One pass over rf: produce xo (N,D) bf16, xa = rf+pe[sig] (N,D) bf16,
// and vsc[n] = sum_d rf[d,n]*u[d]. 64 tokens per block.
__global__ __launch_bounds__(256)
void k_prep(const float* __restrict__ rf, const int* __restrict__ sig,
            const float* __restrict__ pe, const float* __restrict__ u,
            ushort_t* __restrict__ xo, ushort_t* __restrict__ xa,
            float* __restrict__ vsc) {
    __shared__ ushort_t so[64][136];
    __shared__ ushort_t sa[64][136];
    __shared__ float pel[5 * 128];
    __shared__ float ul[128];
    __shared__ int sigl[64];
    __shared__ f32x4 red[16][16];
    const int t = threadIdx.x;
    const int n0 = blockIdx.x * 64;
    if (t < 64) sigl[t] = sig[n0 + t];
    __syncthreads();
    const int dl = t >> 4, tg = t & 15;
    const int sg[4] = {sigl[tg * 4], sigl[tg * 4 + 1], sigl[tg * 4 + 2], sigl[tg * 4 + 3]};
    const int tok = t >> 2, part = t & 3;
    f32x4 vacc = (f32x4)(0.f);

    for (int c = 0; c < 8; ++c) {
        const int d0 = c * 128;
        for (int i = t; i < 640; i += 256) pel[i] = pe[(i >> 7) * DD + d0 + (i & 127)];
        if (t < 128) ul[t] = u[d0 + t];
        __syncthreads();
#pragma unroll
        for (int s = 0; s < 8; ++s) {
            const int dli = s * 16 + dl;
            const f32x4 x = *(const f32x4*)&rf[(size_t)(d0 + dli) * NN + n0 + tg * 4];
            vacc += x * ul[dli];
            ushort_t oo[4], aa[4];
#pragma unroll
            for (int j = 0; j < 4; ++j) {
                oo[j] = f2bf(x[j]);
                aa[j] = f2bf(x[j] + pel[sg[j] * 128 + dli]);
            }
#pragma unroll
            for (int j = 0; j < 4; ++j) {
                so[tg * 4 + j][dli] = oo[j];
                sa[tg * 4 + j][dli] = aa[j];
            }
        }
        __syncthreads();
#pragma unroll
        for (int i = 0; i < 4; ++i) {
            const int off = part * 32 + i * 8;
            *(short8*)&xo[(size_t)(n0 + tok) * DD + d0 + off] = *(const short8*)&so[tok][off];
            *(short8*)&xa[(size_t)(n0 + tok) * DD + d0 + off] = *(const short8*)&sa[tok][off];
        }
        __syncthreads();
    }
    red[dl][tg] = vacc;
    __syncthreads();
    if (t < 64) {
        float s = 0.f;
#pragma unroll
        for (int i = 0; i < 16; ++i) s += ((const float*)&red[i][t >> 2])[t & 3];
        vsc[n0 + t] = s;
    }
}

// ---------------------------------------------------------------------------
// Cast Wq / Wk to bf16.
__global__ void k_wcast(const float* __restrict__ Wq, const float* __restrict__ Wk,
                        ushort_t* __restrict__ wqb, ushort_t* __restrict__ wkb) {
    const int idx = (blockIdx.x * 256 + threadIdx.x) * 8;
    const float* src = blockIdx.y ? Wk : Wq;
    ushort_t* dst = blockIdx.y ? wkb : wqb;
    f32x4 a = *(const f32x4*)&src[idx];
    f32x4 b = *(const f32x4*)&src[idx + 4];
    short8 o;
#pragma unroll
    for (int j = 0; j < 4; ++j) { o[j] = (short)f2bf(a[j]); o[4 + j] = (short)f2bf(b[j]); }
    *(short8*)&dst[idx] = o;
}

// ---------------------------------------------------------------------------
// Projection GEMM: out[n, d'] = bf16( scale*( sum_d x[n,d]*W[d',d] + bias[d'] ) ).
// R8-proven version: 128x128 tile, BK=64, 2-barrier loop, 64x64 wave tiles.
__global__ __launch_bounds__(256, 2)
void k_pgemm(const ushort_t* __restrict__ xb, const ushort_t* __restrict__ wb,
             const float* __restrict__ bias, float scale, ushort_t* __restrict__ outb) {
    __shared__ ushort_t as_[128 * 64];
    __shared__ ushort_t bs_[128 * 64];
    const int t = threadIdx.x;
    const int wv = t >> 6, ln = t & 63;
    const int wr = wv >> 1, wc = wv & 1;
    const int l15 = ln & 15, lhi = ln >> 4;
    const int n0 = blockIdx.x * 128;   // tokens
    const int m0 = blockIdx.y * 128;   // d'
    const int srow = wv * 32;
    const int lr = ln >> 3, lc = ln & 7;
    const int swz = lc ^ lr;

    f32x4 acc[4][4];
#pragma unroll
    for (int a = 0; a < 4; ++a)
#pragma unroll
        for (int b = 0; b < 4; ++b) acc[a][b] = (f32x4)(0.f);

    for (int kk = 0; kk < DD; kk += 64) {
        __syncthreads();
#pragma unroll
        for (int i = 0; i < 4; ++i) {
            const int tok = srow + i * 8 + lr;
            gload_lds16(wb + (size_t)(m0 + tok) * DD + kk + (swz << 3), as_ + (srow + i * 8) * 64);
            gload_lds16(xb + (size_t)(n0 + tok) * DD + kk + (swz << 3), bs_ + (srow + i * 8) * 64);
        }
        __syncthreads();
#pragma unroll
        for (int kp = 0; kp < 2; ++kp) {
            short8 af[4], bf_[4];
#pragma unroll
            for (int mi = 0; mi < 4; ++mi) {
                int r = wr * 64 + mi * 16 + l15;
                int cch = (kp * 4 + lhi) ^ (r & 7);
                af[mi] = *(const short8*)(as_ + r * 64 + cch * 8);
            }
#pragma unroll
            for (int ni = 0; ni < 4; ++ni) {
                int r = wc * 64 + ni * 16 + l15;
                int cch = (kp * 4 + lhi) ^ (r & 7);
                bf_[ni] = *(const short8*)(bs_ + r * 64 + cch * 8);
            }
#pragma unroll
            for (int mi = 0; mi < 4; ++mi)
#pragma unroll
                for (int ni = 0; ni < 4; ++ni)
                    acc[mi][ni] = __builtin_amdgcn_mfma_f32_16x16x32_bf16(
                        af[mi], bf_[ni], acc[mi][ni], 0, 0, 0);
        }
    }
    float bb[4][4];
#pragma unroll
    for (int mi = 0; mi < 4; ++mi) {
        f32x4 b4 = *(const f32x4*)&bias[m0 + wr * 64 + mi * 16 + lhi * 4];
#pragma unroll
        for (int r = 0; r < 4; ++r) bb[mi][r] = b4[r];
    }
#pragma unroll
    for (int mi = 0; mi < 4; ++mi)
#pragma unroll
        for (int ni = 0; ni < 4; ++ni) {
            ushort4_t o;
#pragma unroll
            for (int r = 0; r < 4; ++r) o[r] = f2bf((acc[mi][ni][r] + bb[mi][r]) * scale);
            *(ushort4_t*)&outb[(size_t)(n0 + wc * 64 + ni * 16 + l15) * DD +
                               m0 + wr * 64 + mi * 16 + lhi * 4] = o;
        }
}

// ---------------------------------------------------------------------------
// Fused MFMA scores + softmax (no max subtraction; scores bounded) + scalar-V sum.
// R8 structure: 256 threads = 4 waves (2M x 2N), block tile 128x256, wave 64x128,
// BK=32, 3-ring LDS (72 KiB) -> 2 blocks/CU, stage 2 ahead, counted vmcnt(6).
__global__ __launch_bounds__(256, 2)
void k_attn(const ushort_t* __restrict__ qb, const ushort_t* __restrict__ kb,
            const float* __restrict__ vsc, float* __restrict__ pl,
            float* __restrict__ pa) {
    __shared__ ushort_t As[3][128 * 32];
    __shared__ ushort_t Bs[3][256 * 32];
    const int t = threadIdx.x;
    const int wv = t >> 6, ln = t & 63;
    const int wm = wv >> 1, wn = wv & 1;     // wave tile: rows wm*64, cols wn*128
    const int l15 = ln & 15, lhi = ln >> 4;

    // XCD-aware bijective swizzle: 490 blocks, q=61, r=2.
    const int g = blockIdx.x;
    const int xcd = g & 7, gq = g >> 3;
    const int L = (xcd < 2) ? xcd * 62 + gq : 124 + (xcd - 2) * 61 + gq;
    const int bx = L / NSPLIT, split = L % NSPLIT;
    const int m0 = bx * 128;

    // staging coords: 64B rows (BK=32); chunk = 16B; swizzle chunk ^= (row>>1)&3
    const int srr = ln >> 2;          // row within 16-row group
    const int slc = ln & 3;           // chunk within row

    float rl[4][4], ra[4][4];
#pragma unroll
    for (int a = 0; a < 4; ++a)
#pragma unroll
        for (int b = 0; b < 4; ++b) { rl[a][b] = 0.f; ra[a][b] = 0.f; }

    f32x4 acc[4][8];
#pragma unroll
    for (int a = 0; a < 4; ++a)
#pragma unroll
        for (int b = 0; b < 8; ++b) acc[a][b] = (f32x4)(0.f);

// stage one K-step's A+B tiles (6 gloads/lane) into ring buffer BUF
#define STAGE(BUF, SNT, KKO)                                                      \
    {                                                                             \
        const int nn0_ = (SNT) * 256;                                             \
        ushort_t* Ad = &As[BUF][0];                                               \
        ushort_t* Bd = &Bs[BUF][0];                                               \
        _Pragma("unroll")                                                         \
        for (int i = 0; i < 2; ++i) {                                             \
            const int row = wv * 32 + i * 16 + srr;                               \
            const int sc = slc ^ ((row >> 1) & 3);                                \
            gload_lds16(qb + (size_t)(m0 + row) * DD + (KKO) + sc * 8,            \
                        Ad + (wv * 32 + i * 16) * 32);                            \
        }                                                                         \
        _Pragma("unroll")                                                         \
        for (int i = 0; i < 4; ++i) {                                             \
            const int row = wv * 64 + i * 16 + srr;                               \
            const int sc = slc ^ ((row >> 1) & 3);                                \
            gload_lds16(kb + (size_t)(nn0_ + row) * DD + (KKO) + sc * 8,          \
                        Bd + (wv * 64 + i * 16) * 32);                            \
        }                                                                         \
    }

    // prologue: stage steps 0 and 1; wait for step 0 only (6 newest may remain)
    STAGE(0, split, 0);
    STAGE(1, split, 32);
    asm volatile("s_waitcnt vmcnt(6)" ::: "memory");
    __builtin_amdgcn_s_barrier();

    int cur = 0;
    for (int nt = split; nt < NTILES; nt += NSPLIT) {
        const int n0 = nt * 256;
        for (int kidx = 0; kidx < 32; ++kidx) {
            // epilogue vv prefetch FIRST so its wait is counted, not a drain
            float vv[8];
            if (kidx == 31) {
#pragma unroll
                for (int ni = 0; ni < 8; ++ni) vv[ni] = vsc[n0 + wn * 128 + ni * 16 + l15];
            }
            // stage step s+2 into ring buffer (s+2)%3
            int nk2 = kidx + 2, nnt2 = nt;
            if (nk2 >= 32) { nk2 -= 32; nnt2 += NSPLIT; }
            const bool st = (nnt2 < NTILES);
            if (st) {
                int b2 = cur + 2; if (b2 >= 3) b2 -= 3;
                STAGE(b2, nnt2, nk2 * 32);
            }
            // fragment reads from current buffer (2-way bank aliasing max = free)
            const ushort_t* Ab = &As[cur][0];
            const ushort_t* Bb = &Bs[cur][0];
            short8 af[4], bfr[8];
#pragma unroll
            for (int mi = 0; mi < 4; ++mi) {
                const int r = wm * 64 + mi * 16 + l15;
                const int c = lhi ^ ((r >> 1) & 3);
                af[mi] = *(const short8*)(Ab + r * 32 + c * 8);
            }
#pragma unroll
            for (int ni = 0; ni < 8; ++ni) {
                const int r = wn * 128 + ni * 16 + l15;
                const int c = lhi ^ ((r >> 1) & 3);
                bfr[ni] = *(const short8*)(Bb + r * 32 + c * 8);
            }
            __builtin_amdgcn_s_setprio(1);
#pragma unroll
            for (int ni = 0; ni < 8; ++ni)
#pragma unroll
                for (int mi = 0; mi < 4; ++mi)
                    acc[mi][ni] = __builtin_amdgcn_mfma_f32_16x16x32_bf16(
                        af[mi], bfr[ni], acc[mi][ni], 0, 0, 0);
            __builtin_amdgcn_s_setprio(0);

            if (kidx == 31) {
                // ---- softmax epilogue, no max subtraction (shift-invariant) ----
#pragma unroll
                for (int mi = 0; mi < 4; ++mi) {
#pragma unroll
                    for (int r = 0; r < 4; ++r) {
                        float sp = 0.f, sv = 0.f;
#pragma unroll
                        for (int ni = 0; ni < 8; ++ni) {
                            float p = __expf(acc[mi][ni][r]);
                            sp += p; sv += p * vv[ni];
                        }
                        sp += __shfl_xor(sp, 1); sv += __shfl_xor(sv, 1);
                        sp += __shfl_xor(sp, 2); sv += __shfl_xor(sv, 2);
                        sp += __shfl_xor(sp, 4); sv += __shfl_xor(sv, 4);
                        sp += __shfl_xor(sp, 8); sv += __shfl_xor(sv, 8);
                        rl[mi][r] += sp;
                        ra[mi][r] += sv;
                    }
                }
#pragma unroll
                for (int a = 0; a < 4; ++a)
#pragma unroll
                    for (int b = 0; b < 8; ++b) acc[a][b] = (f32x4)(0.f);
            }
            // T4: wait only for the PREVIOUS step's loads (6 newest outstanding ok)
            if (st) asm volatile("s_waitcnt vmcnt(6)" ::: "memory");
            else    asm volatile("s_waitcnt vmcnt(0)" ::: "memory");
            __builtin_amdgcn_s_barrier();
            cur = (cur + 1 == 3) ? 0 : cur + 1;
        }
    }
#undef STAGE
    // write partials: slab = split*2 + wn
    if (l15 == 0) {
        const size_t slab = (size_t)(split * 2 + wn) * NN;
#pragma unroll
        for (int mi = 0; mi < 4; ++mi)
#pragma unroll
            for (int r = 0; r < 4; ++r) {
                int row = m0 + wm * 64 + mi * 16 + lhi * 4 + r;
                pl[slab + row] = rl[mi][r];
                pa[slab + row] = ra[mi][r];
            }
    }
}

// ---------------------------------------------------------------------------
// Merge partials; add conv-head constants (c = bv·cw folded here) + sigmoid.
__global__ void k_comb(const float* __restrict__ pl, const float* __restrict__ pa,
                       const float* __restrict__ cptr, const float* __restrict__ cb,
                       float* __restrict__ out) {
    int n = blockIdx.x * 256 + threadIdx.x;
    float l = 0.f, a = 0.f;
#pragma unroll
    for (int s = 0; s < NPART; ++s) {
        l += pl[(size_t)s * NN + n];
        a += pa[(size_t)s * NN + n];
    }
    float x = a / l + cptr[0] + cb[0];
    out[n] = 1.f / (1.f + __expf(-x));
}

// ---------------------------------------------------------------------------
extern "C" void kernel_launch(void* const* d_in, const int* in_sizes, int n_in,
                              void* d_out, int out_size, void* d_ws, size_t ws_size,
                              hipStream_t stream) {
    const int* sig = (const int*)d_in[0];
    const float* rf = (const float*)d_in[1];
    const float* pe = (const float*)d_in[3];
    const float* Wq = (const float*)d_in[4];
    const float* bq = (const float*)d_in[5];
    const float* Wk = (const float*)d_in[6];
    const float* bk = (const float*)d_in[7];
    const float* Wv = (const float*)d_in[8];
    const float* bv = (const float*)d_in[9];
    const float* cw = (const float*)d_in[10];
    const float* cb = (const float*)d_in[11];
    float* out = (float*)d_out;

    ushort_t* buf0 = (ushort_t*)d_ws;             // xo, later qb
    ushort_t* buf1 = buf0 + (size_t)NN * DD;      // xa
    ushort_t* buf2 = buf1 + (size_t)NN * DD;      // kb
    ushort_t* wqb = buf2 + (size_t)NN * DD;
    ushort_t* wkb = wqb + (size_t)DD * DD;
    float* u = (float*)(wkb + (size_t)DD * DD);   // 1024
    float* cptr = u + 1024;                       // 16 reserved
    float* vsc = u + 1024 + 16;                   // NN
    float* pl = vsc + NN;                         // NPART*NN
    float* pa = pl + (size_t)NPART * NN;

    hipMemsetAsync(u, 0, (1024 + 16) * sizeof(float), stream);
    k_u<<<dim3(4, 16), 256, 0, stream>>>(Wv, cw, bv, u, cptr);
    k_prep<<<196, 256, 0, stream>>>(rf, sig, pe, u, buf0, buf1, vsc);
    k_wcast<<<dim3(512, 2), 256, 0, stream>>>(Wq, Wk, wqb, wkb);
    k_pgemm<<<dim3(98, 8), 256, 0, stream>>>(buf0, wkb, bk, 1.0f, buf2);      // K
    k_pgemm<<<dim3(98, 8), 256, 0, stream>>>(buf1, wqb, bq, 0.03125f, buf0);  // Q
    k_attn<<<490, 256, 0, stream>>>(buf0, buf2, vsc, pl, pa);
    k_comb<<<NN / 256, 256, 0, stream>>>(pl, pa, cptr, cb, out);
}